// Round 4
// baseline (1359.895 us; speedup 1.0000x reference)
//
#include <hip/hip_runtime.h>
#include <hip/hip_bf16.h>

#define NG 512  // NUM_GRAPHS
#define EPS_BN 1e-5f

__device__ __forceinline__ float4 f4add(float4 a, float4 b) {
    a.x += b.x; a.y += b.y; a.z += b.z; a.w += b.w; return a;
}
__device__ __forceinline__ float4 f4fma(float s, float4 b, float4 a) {
    a.x = fmaf(s, b.x, a.x); a.y = fmaf(s, b.y, a.y);
    a.z = fmaf(s, b.z, a.z); a.w = fmaf(s, b.w, a.w); return a;
}
__device__ __forceinline__ float4 f4scale(float s, float4 a) {
    a.x *= s; a.y *= s; a.z *= s; a.w *= s; return a;
}
__device__ __forceinline__ float4 bnrelu4(float4 v, float4 sc, float4 sh) {
    float4 r;
    r.x = fmaxf(fmaf(sc.x, v.x, sh.x), 0.f);
    r.y = fmaxf(fmaf(sc.y, v.y, sh.y), 0.f);
    r.z = fmaxf(fmaf(sc.z, v.z, sh.z), 0.f);
    r.w = fmaxf(fmaf(sc.w, v.w, sh.w), 0.f);
    return r;
}
__device__ __forceinline__ void bnparam(float sm, float sq, float ga, float bt,
                                        float invN, float& sc, float& sh) {
    float m = sm * invN;
    float var = fmaf(-m, m, sq * invN);
    sc = ga * rsqrtf(var + EPS_BN);
    sh = fmaf(-m, sc, bt);
}

// ---------------- degree / normalization ----------------

__global__ void k_count(const int* __restrict__ dst, int* __restrict__ cnt, int E) {
    int i = blockIdx.x * blockDim.x + threadIdx.x;
    if (i < E) atomicAdd(&cnt[dst[i]], 1);
}

__global__ void k_dinv(const int* __restrict__ cnt, float* __restrict__ dinv, int N) {
    int i = blockIdx.x * blockDim.x + threadIdx.x;
    if (i < N) dinv[i] = rsqrtf((float)cnt[i] + 1.0f);  // +1 self-loop
}

// ---------------- exclusive prefix-sum over cnt -> rowptr ----------------

#define SCAN_T 256
#define SCAN_I 4  // 1024 elements per block

__global__ void k_scan1(const int* __restrict__ in, int* __restrict__ out,
                        int* __restrict__ bsum, int N) {
    __shared__ int lds[SCAN_T];
    int t = threadIdx.x;
    int base = blockIdx.x * (SCAN_T * SCAN_I) + t * SCAN_I;
    int v[SCAN_I];
    int sum = 0;
#pragma unroll
    for (int i = 0; i < SCAN_I; ++i) {
        int idx = base + i;
        v[i] = (idx < N) ? in[idx] : 0;
        sum += v[i];
    }
    lds[t] = sum;
    __syncthreads();
    for (int o = 1; o < SCAN_T; o <<= 1) {
        int a = (t >= o) ? lds[t - o] : 0;
        __syncthreads();
        lds[t] += a;
        __syncthreads();
    }
    int run = lds[t] - sum;
#pragma unroll
    for (int i = 0; i < SCAN_I; ++i) {
        int idx = base + i;
        if (idx < N) out[idx] = run;
        run += v[i];
    }
    if (t == SCAN_T - 1) bsum[blockIdx.x] = lds[SCAN_T - 1];
}

__global__ void k_scan2(int* __restrict__ bs, int nb) {
    __shared__ int lds[SCAN_T];
    int t = threadIdx.x;
    int runbase = 0;
    for (int start = 0; start < nb; start += SCAN_T) {
        int idx = start + t;
        int v = (idx < nb) ? bs[idx] : 0;
        lds[t] = v;
        __syncthreads();
        for (int o = 1; o < SCAN_T; o <<= 1) {
            int a = (t >= o) ? lds[t - o] : 0;
            __syncthreads();
            lds[t] += a;
            __syncthreads();
        }
        if (idx < nb) bs[idx] = runbase + lds[t] - v;
        int tot = lds[SCAN_T - 1];
        __syncthreads();
        runbase += tot;
    }
}

__global__ void k_scan3(int* __restrict__ out, const int* __restrict__ bs, int N) {
    int add = bs[blockIdx.x];
    int base = blockIdx.x * (SCAN_T * SCAN_I) + threadIdx.x * SCAN_I;
#pragma unroll
    for (int i = 0; i < SCAN_I; ++i) {
        int idx = base + i;
        if (idx < N) out[idx] += add;
    }
}

// ---------------- bucket edges by dst (CSR), pre-bake per-edge weight dinv[src] ----------------

__global__ void k_bucket(const int* __restrict__ src, const int* __restrict__ dst,
                         const float* __restrict__ dinv, const int* __restrict__ rowptr,
                         int* __restrict__ fill, int* __restrict__ esrc,
                         float* __restrict__ ewt, int E) {
    int e = blockIdx.x * blockDim.x + threadIdx.x;
    if (e >= E) return;
    int d = dst[e], s = src[e];
    int pos = rowptr[d] + atomicAdd(&fill[d], 1);
    esrc[pos] = s;
    ewt[pos] = dinv[s];
}

// ---------------- gather over raw x (layer 1 input, C=6): 1 thread per node ----------------

__global__ void k_gather_x(const int* __restrict__ rowptr, const int* __restrict__ cnt,
                           const int* __restrict__ esrc, const float* __restrict__ ewt,
                           const float* __restrict__ dinv, const float* __restrict__ x,
                           float* __restrict__ out, int N) {
    int n = blockIdx.x * blockDim.x + threadIdx.x;
    if (n >= N) return;
    const float2* x2 = reinterpret_cast<const float2*>(x);
    float2* o2 = reinterpret_cast<float2*>(out);
    int beg = rowptr[n], end = beg + cnt[n];
    float di = dinv[n];
    size_t b3 = (size_t)n * 3;
    float2 p0 = x2[b3], p1 = x2[b3 + 1], p2 = x2[b3 + 2];
    float a0 = di * p0.x, a1 = di * p0.y, a2 = di * p1.x;
    float a3 = di * p1.y, a4 = di * p2.x, a5 = di * p2.y;
    for (int e = beg; e < end; ++e) {
        int s = esrc[e];
        float w = ewt[e];
        size_t s3 = (size_t)s * 3;
        float2 q0 = x2[s3], q1 = x2[s3 + 1], q2 = x2[s3 + 2];
        a0 = fmaf(w, q0.x, a0); a1 = fmaf(w, q0.y, a1);
        a2 = fmaf(w, q1.x, a2); a3 = fmaf(w, q1.y, a3);
        a4 = fmaf(w, q2.x, a4); a5 = fmaf(w, q2.y, a5);
    }
    o2[b3]     = make_float2(di * a0, di * a1);
    o2[b3 + 1] = make_float2(di * a2, di * a3);
    o2[b3 + 2] = make_float2(di * a4, di * a5);
}

// ---------------- gather with fused BN+ReLU, float4 per thread ----------------

template <int C>
__global__ void k_gather_bn(const int* __restrict__ rowptr, const int* __restrict__ cnt,
                            const int* __restrict__ esrc, const float* __restrict__ ewt,
                            const float* __restrict__ dinv, const float* __restrict__ h,
                            const float* __restrict__ sums, const float* __restrict__ sumsq,
                            const float* __restrict__ gam, const float* __restrict__ bet,
                            float* __restrict__ out, int N, float invN) {
    constexpr int TPN = C / 4;     // threads per node
    constexpr int NPB = 256 / TPN; // nodes per block
    int t = threadIdx.x;
    int c4 = t & (TPN - 1);
    int n = blockIdx.x * NPB + t / TPN;
    if (n >= N) return;
    float4 sm = reinterpret_cast<const float4*>(sums)[c4];
    float4 sq = reinterpret_cast<const float4*>(sumsq)[c4];
    float4 ga = reinterpret_cast<const float4*>(gam)[c4];
    float4 bt = reinterpret_cast<const float4*>(bet)[c4];
    float4 sc, sh;
    bnparam(sm.x, sq.x, ga.x, bt.x, invN, sc.x, sh.x);
    bnparam(sm.y, sq.y, ga.y, bt.y, invN, sc.y, sh.y);
    bnparam(sm.z, sq.z, ga.z, bt.z, invN, sc.z, sh.z);
    bnparam(sm.w, sq.w, ga.w, bt.w, invN, sc.w, sh.w);
    const float4* h4 = reinterpret_cast<const float4*>(h);
    int beg = rowptr[n], end = beg + cnt[n];
    float di = dinv[n];
    float4 acc = f4scale(di, bnrelu4(h4[(size_t)n * TPN + c4], sc, sh));  // self-loop
    int e = beg;
    for (; e + 1 < end; e += 2) {
        int s0 = esrc[e], s1 = esrc[e + 1];
        float w0 = ewt[e], w1 = ewt[e + 1];
        float4 v0 = h4[(size_t)s0 * TPN + c4];
        float4 v1 = h4[(size_t)s1 * TPN + c4];
        acc = f4fma(w0, bnrelu4(v0, sc, sh), acc);
        acc = f4fma(w1, bnrelu4(v1, sc, sh), acc);
    }
    if (e < end)
        acc = f4fma(ewt[e], bnrelu4(h4[(size_t)esrc[e] * TPN + c4], sc, sh), acc);
    reinterpret_cast<float4*>(out)[(size_t)n * TPN + c4] = f4scale(di, acc);
}

// ---------------- matmul + fused BN-stats; W staged in LDS; 2-row ILP ----------------

template <int CIN, int COUT, bool LDSW>
__global__ void k_mm_stats(const float* __restrict__ in, const float* __restrict__ W,
                           float* __restrict__ out, float* __restrict__ sums,
                           float* __restrict__ sumsq, int N) {
    constexpr int CG = COUT / 4;    // channel groups of 4
    constexpr int RPB = 256 / CG;   // rows per block-iteration
    __shared__ float4 red1[256];
    __shared__ float4 red2[256];
    __shared__ float4 lw[LDSW ? CIN * CG : 1];
    int t = threadIdx.x;
    int gi = t % CG;
    int r0 = t / CG;
    int c0 = gi * 4;
    const float4* W4 = reinterpret_cast<const float4*>(W);
    if constexpr (LDSW) {
        for (int i = t; i < CIN * CG; i += 256) lw[i] = W4[i];
        __syncthreads();
    }
    auto wload = [&](int k) -> float4 {
        if constexpr (LDSW) return lw[k * CG + gi];
        else return W4[k * CG + gi];
    };
    float4 s = {0, 0, 0, 0}, s2 = {0, 0, 0, 0};
    const int stride = gridDim.x * RPB;
    int row = blockIdx.x * RPB + r0;
    for (; row + stride < N; row += 2 * stride) {
        int rowB = row + stride;
        float4 a0 = {0, 0, 0, 0}, a1 = {0, 0, 0, 0};
        if constexpr (CIN % 4 == 0) {
            const float4* i0 = reinterpret_cast<const float4*>(in + (size_t)row * CIN);
            const float4* i1 = reinterpret_cast<const float4*>(in + (size_t)rowB * CIN);
#pragma unroll
            for (int k4 = 0; k4 < CIN / 4; ++k4) {
                float4 v0 = i0[k4], v1 = i1[k4];
                float4 w;
                w = wload(k4 * 4 + 0); a0 = f4fma(v0.x, w, a0); a1 = f4fma(v1.x, w, a1);
                w = wload(k4 * 4 + 1); a0 = f4fma(v0.y, w, a0); a1 = f4fma(v1.y, w, a1);
                w = wload(k4 * 4 + 2); a0 = f4fma(v0.z, w, a0); a1 = f4fma(v1.z, w, a1);
                w = wload(k4 * 4 + 3); a0 = f4fma(v0.w, w, a0); a1 = f4fma(v1.w, w, a1);
            }
        } else {
#pragma unroll
            for (int k = 0; k < CIN; ++k) {
                float4 w = wload(k);
                a0 = f4fma(in[(size_t)row * CIN + k], w, a0);
                a1 = f4fma(in[(size_t)rowB * CIN + k], w, a1);
            }
        }
        reinterpret_cast<float4*>(out + (size_t)row * COUT)[gi] = a0;
        reinterpret_cast<float4*>(out + (size_t)rowB * COUT)[gi] = a1;
        s = f4add(s, f4add(a0, a1));
        s2.x = fmaf(a0.x, a0.x, fmaf(a1.x, a1.x, s2.x));
        s2.y = fmaf(a0.y, a0.y, fmaf(a1.y, a1.y, s2.y));
        s2.z = fmaf(a0.z, a0.z, fmaf(a1.z, a1.z, s2.z));
        s2.w = fmaf(a0.w, a0.w, fmaf(a1.w, a1.w, s2.w));
    }
    for (; row < N; row += stride) {
        float4 a0 = {0, 0, 0, 0};
        if constexpr (CIN % 4 == 0) {
            const float4* i0 = reinterpret_cast<const float4*>(in + (size_t)row * CIN);
#pragma unroll
            for (int k4 = 0; k4 < CIN / 4; ++k4) {
                float4 v0 = i0[k4];
                a0 = f4fma(v0.x, wload(k4 * 4 + 0), a0);
                a0 = f4fma(v0.y, wload(k4 * 4 + 1), a0);
                a0 = f4fma(v0.z, wload(k4 * 4 + 2), a0);
                a0 = f4fma(v0.w, wload(k4 * 4 + 3), a0);
            }
        } else {
#pragma unroll
            for (int k = 0; k < CIN; ++k)
                a0 = f4fma(in[(size_t)row * CIN + k], wload(k), a0);
        }
        reinterpret_cast<float4*>(out + (size_t)row * COUT)[gi] = a0;
        s = f4add(s, a0);
        s2.x = fmaf(a0.x, a0.x, s2.x);
        s2.y = fmaf(a0.y, a0.y, s2.y);
        s2.z = fmaf(a0.z, a0.z, s2.z);
        s2.w = fmaf(a0.w, a0.w, s2.w);
    }
    red1[t] = s; red2[t] = s2;
    for (int hh = RPB / 2; hh > 0; hh >>= 1) {
        __syncthreads();
        if (r0 < hh) {
            red1[t] = f4add(red1[t], red1[t + hh * CG]);
            red2[t] = f4add(red2[t], red2[t + hh * CG]);
        }
    }
    if (r0 == 0) {
        float4 a = red1[t], b = red2[t];
        atomicAdd(&sums[c0 + 0], a.x); atomicAdd(&sums[c0 + 1], a.y);
        atomicAdd(&sums[c0 + 2], a.z); atomicAdd(&sums[c0 + 3], a.w);
        atomicAdd(&sumsq[c0 + 0], b.x); atomicAdd(&sumsq[c0 + 1], b.y);
        atomicAdd(&sumsq[c0 + 2], b.z); atomicAdd(&sumsq[c0 + 3], b.w);
    }
}

// ---------------- segmented segment_max with fused BN+ReLU (batch is sorted) ----------------

__global__ void k_segmax_bn(const float* __restrict__ h, const int* __restrict__ batch,
                            const float* __restrict__ sums, const float* __restrict__ sumsq,
                            const float* __restrict__ gam, const float* __restrict__ bet,
                            float* __restrict__ pool, int N, float invN) {
    int t = threadIdx.x;
    int c = t & 127;
    int sub = t >> 7;
    int base = blockIdx.x * 64 + sub * 32;
    if (base >= N) return;
    float sc, sh;
    bnparam(sums[c], sumsq[c], gam[c], bet[c], invN, sc, sh);
    int cur = batch[base];
    float mx = fmaxf(fmaf(sc, h[(size_t)base * 128 + c], sh), 0.f);
    int lim = min(32, N - base);
    for (int i = 1; i < lim; ++i) {
        int n = base + i;
        int b = batch[n];
        float v = fmaxf(fmaf(sc, h[(size_t)n * 128 + c], sh), 0.f);
        if (b != cur) {  // uniform across the 128 lanes of this sub-chunk
            atomicMax(reinterpret_cast<int*>(pool) + (cur << 7) + c, __float_as_int(mx));
            cur = b; mx = v;
        } else {
            mx = fmaxf(mx, v);
        }
    }
    atomicMax(reinterpret_cast<int*>(pool) + (cur << 7) + c, __float_as_int(mx));
}

// ---------------- head: BN4+ReLU on load, FC2, row-L2-normalize ----------------

__global__ void k_head(const float* __restrict__ Z, const float* __restrict__ sums,
                       const float* __restrict__ sumsq, const float* __restrict__ gam,
                       const float* __restrict__ bet, const float* __restrict__ Wf2,
                       const float* __restrict__ bf2, float* __restrict__ out) {
    int g = blockIdx.x, c = threadIdx.x;  // 64 threads = 1 wave
    __shared__ float row[128];
    const float invG = 1.0f / (float)NG;
    for (int j = c; j < 128; j += 64) {
        float sc, sh;
        bnparam(sums[j], sumsq[j], gam[j], bet[j], invG, sc, sh);
        row[j] = fmaxf(fmaf(sc, Z[(g << 7) + j], sh), 0.f);
    }
    __syncthreads();
    float acc = bf2[c];
#pragma unroll
    for (int k = 0; k < 128; ++k) acc = fmaf(row[k], Wf2[k * 64 + c], acc);
    float ss = acc * acc;
#pragma unroll
    for (int off = 32; off; off >>= 1) ss += __shfl_xor(ss, off);
    out[(g << 6) + c] = acc / fmaxf(sqrtf(ss), 1e-12f);
}

// ---------------- launch ----------------

extern "C" void kernel_launch(void* const* d_in, const int* in_sizes, int n_in,
                              void* d_out, int out_size, void* d_ws, size_t ws_size,
                              hipStream_t stream) {
    const float* x    = (const float*)d_in[0];
    const int*   src  = (const int*)d_in[1];
    const int*   dst  = (const int*)d_in[2];
    const int*   batch= (const int*)d_in[3];
    const float* W1   = (const float*)d_in[4];   // b1 cancels in BN
    const float* g1   = (const float*)d_in[6];
    const float* be1  = (const float*)d_in[7];
    const float* W2   = (const float*)d_in[8];   // b2 cancels
    const float* g2   = (const float*)d_in[10];
    const float* be2  = (const float*)d_in[11];
    const float* W3   = (const float*)d_in[12];  // b3 cancels
    const float* g3   = (const float*)d_in[14];
    const float* be3  = (const float*)d_in[15];
    const float* Wf1  = (const float*)d_in[16];  // bf1 cancels
    const float* g4   = (const float*)d_in[18];
    const float* be4  = (const float*)d_in[19];
    const float* Wf2  = (const float*)d_in[20];
    const float* bf2  = (const float*)d_in[21];
    float* out = (float*)d_out;

    const int N = in_sizes[0] / 6;
    const int E = in_sizes[1];
    const int nScanBlocks = (N + SCAN_T * SCAN_I - 1) / (SCAN_T * SCAN_I);

    // workspace carve-up
    char* ws = (char*)d_ws;
    size_t off = 0;
    auto carve = [&](size_t bytes) {
        void* p = ws + off;
        off += (bytes + 255) & ~(size_t)255;
        return p;
    };
    int*   cnt    = (int*)carve((size_t)N * 4);
    float* dinv   = (float*)carve((size_t)N * 4);
    int*   rowptr = (int*)carve((size_t)N * 4);
    int*   fill   = (int*)carve((size_t)N * 4);
    int*   bsum   = (int*)carve((size_t)4096 * 4);
    int*   esrc   = (int*)carve((size_t)E * 4);
    float* ewt    = (float*)carve((size_t)E * 4);
    float* G      = (float*)carve((size_t)N * 64 * 4);   // gather outputs (max C=64)
    float* H      = (float*)carve((size_t)N * 128 * 4);  // matmul outputs (max C=128)
    float* stats  = (float*)carve(704 * 4);
    float* pool   = (float*)carve((size_t)NG * 128 * 4);
    float* Z      = (float*)carve((size_t)NG * 128 * 4);
    float* s1 = stats;        // L1 sums/sumsq
    float* s2 = stats + 64;   // L2
    float* s3 = stats + 192;  // L3
    float* s4 = stats + 448;  // head

    const float invN = 1.0f / (float)N;

    // ---- build dst-sorted CSR (once; reused by all 3 layers) ----
    hipMemsetAsync(cnt, 0, (size_t)N * 4, stream);
    hipMemsetAsync(fill, 0, (size_t)N * 4, stream);
    hipMemsetAsync(stats, 0, 704 * 4, stream);
    hipMemsetAsync(pool, 0, (size_t)NG * 128 * 4, stream);
    k_count<<<(E + 255) / 256, 256, 0, stream>>>(dst, cnt, E);
    k_dinv<<<(N + 255) / 256, 256, 0, stream>>>(cnt, dinv, N);
    k_scan1<<<nScanBlocks, SCAN_T, 0, stream>>>(cnt, rowptr, bsum, N);
    k_scan2<<<1, SCAN_T, 0, stream>>>(bsum, nScanBlocks);
    k_scan3<<<nScanBlocks, SCAN_T, 0, stream>>>(rowptr, bsum, N);
    k_bucket<<<(E + 255) / 256, 256, 0, stream>>>(src, dst, dinv, rowptr, fill, esrc, ewt, E);

    // ---- layer 1: aggregate x (C=6), then 6->32 matmul (+stats1) ----
    k_gather_x<<<(N + 255) / 256, 256, 0, stream>>>(rowptr, cnt, esrc, ewt, dinv, x, G, N);
    k_mm_stats<6, 32, true><<<1024, 256, 0, stream>>>(G, W1, H, s1, s1 + 32, N);

    // ---- layer 2: aggregate act1 (C=32), then 32->64 matmul (+stats2) ----
    k_gather_bn<32><<<(N + 31) / 32, 256, 0, stream>>>(
        rowptr, cnt, esrc, ewt, dinv, H, s1, s1 + 32, g1, be1, G, N, invN);
    k_mm_stats<32, 64, true><<<1024, 256, 0, stream>>>(G, W2, H, s2, s2 + 64, N);

    // ---- layer 3: aggregate act2 (C=64), then 64->128 matmul (+stats3) ----
    k_gather_bn<64><<<(N + 15) / 16, 256, 0, stream>>>(
        rowptr, cnt, esrc, ewt, dinv, H, s2, s2 + 64, g2, be2, G, N, invN);
    k_mm_stats<64, 128, true><<<1024, 256, 0, stream>>>(G, W3, H, s3, s3 + 128, N);

    // ---- pooling: segmented segment_max with fused BN3+ReLU ----
    k_segmax_bn<<<(N + 63) / 64, 256, 0, stream>>>(H, batch, s3, s3 + 128, g3, be3, pool, N, invN);

    // ---- head: FC1 (+stats4), then BN4+ReLU+FC2+normalize ----
    k_mm_stats<128, 128, false><<<64, 256, 0, stream>>>(pool, Wf1, Z, s4, s4 + 128, NG);
    k_head<<<NG, 64, 0, stream>>>(Z, s4, s4 + 128, g4, be4, Wf2, bf2, out);
}

// Round 5
// 1181.568 us; speedup vs baseline: 1.1509x; 1.1509x over previous
//
#include <hip/hip_runtime.h>
#include <hip/hip_bf16.h>

#define NG 512  // NUM_GRAPHS
#define EPS_BN 1e-5f

__device__ __forceinline__ float4 f4add(float4 a, float4 b) {
    a.x += b.x; a.y += b.y; a.z += b.z; a.w += b.w; return a;
}
__device__ __forceinline__ float4 f4fma(float s, float4 b, float4 a) {
    a.x = fmaf(s, b.x, a.x); a.y = fmaf(s, b.y, a.y);
    a.z = fmaf(s, b.z, a.z); a.w = fmaf(s, b.w, a.w); return a;
}
__device__ __forceinline__ float4 f4scale(float s, float4 a) {
    a.x *= s; a.y *= s; a.z *= s; a.w *= s; return a;
}
__device__ __forceinline__ float4 bnrelu4(float4 v, float4 sc, float4 sh) {
    float4 r;
    r.x = fmaxf(fmaf(sc.x, v.x, sh.x), 0.f);
    r.y = fmaxf(fmaf(sc.y, v.y, sh.y), 0.f);
    r.z = fmaxf(fmaf(sc.z, v.z, sh.z), 0.f);
    r.w = fmaxf(fmaf(sc.w, v.w, sh.w), 0.f);
    return r;
}
__device__ __forceinline__ void bnparam(float sm, float sq, float ga, float bt,
                                        float invN, float& sc, float& sh) {
    float m = sm * invN;
    float var = fmaf(-m, m, sq * invN);
    sc = ga * rsqrtf(var + EPS_BN);
    sh = fmaf(-m, sc, bt);
}

// ---------------- degree / normalization ----------------

__global__ void k_count(const int* __restrict__ dst, int* __restrict__ cnt, int E) {
    int i = blockIdx.x * blockDim.x + threadIdx.x;
    if (i < E) atomicAdd(&cnt[dst[i]], 1);
}

__global__ void k_dinv(const int* __restrict__ cnt, float* __restrict__ dinv, int N) {
    int i = blockIdx.x * blockDim.x + threadIdx.x;
    if (i < N) dinv[i] = rsqrtf((float)cnt[i] + 1.0f);  // +1 self-loop
}

// ---------------- exclusive prefix-sum over cnt -> rowptr ----------------

#define SCAN_T 256
#define SCAN_I 4  // 1024 elements per block

__global__ void k_scan1(const int* __restrict__ in, int* __restrict__ out,
                        int* __restrict__ bsum, int N) {
    __shared__ int lds[SCAN_T];
    int t = threadIdx.x;
    int base = blockIdx.x * (SCAN_T * SCAN_I) + t * SCAN_I;
    int v[SCAN_I];
    int sum = 0;
#pragma unroll
    for (int i = 0; i < SCAN_I; ++i) {
        int idx = base + i;
        v[i] = (idx < N) ? in[idx] : 0;
        sum += v[i];
    }
    lds[t] = sum;
    __syncthreads();
    for (int o = 1; o < SCAN_T; o <<= 1) {
        int a = (t >= o) ? lds[t - o] : 0;
        __syncthreads();
        lds[t] += a;
        __syncthreads();
    }
    int run = lds[t] - sum;
#pragma unroll
    for (int i = 0; i < SCAN_I; ++i) {
        int idx = base + i;
        if (idx < N) out[idx] = run;
        run += v[i];
    }
    if (t == SCAN_T - 1) bsum[blockIdx.x] = lds[SCAN_T - 1];
}

__global__ void k_scan2(int* __restrict__ bs, int nb) {
    __shared__ int lds[SCAN_T];
    int t = threadIdx.x;
    int runbase = 0;
    for (int start = 0; start < nb; start += SCAN_T) {
        int idx = start + t;
        int v = (idx < nb) ? bs[idx] : 0;
        lds[t] = v;
        __syncthreads();
        for (int o = 1; o < SCAN_T; o <<= 1) {
            int a = (t >= o) ? lds[t - o] : 0;
            __syncthreads();
            lds[t] += a;
            __syncthreads();
        }
        if (idx < nb) bs[idx] = runbase + lds[t] - v;
        int tot = lds[SCAN_T - 1];
        __syncthreads();
        runbase += tot;
    }
}

__global__ void k_scan3(int* __restrict__ out, const int* __restrict__ bs, int N) {
    int add = bs[blockIdx.x];
    int base = blockIdx.x * (SCAN_T * SCAN_I) + threadIdx.x * SCAN_I;
#pragma unroll
    for (int i = 0; i < SCAN_I; ++i) {
        int idx = base + i;
        if (idx < N) out[idx] += add;
    }
}

// ---------------- bucket edges by dst (CSR), pre-bake per-edge weight dinv[src] ----------------

__global__ void k_bucket(const int* __restrict__ src, const int* __restrict__ dst,
                         const float* __restrict__ dinv, const int* __restrict__ rowptr,
                         int* __restrict__ fill, int* __restrict__ esrc,
                         float* __restrict__ ewt, int E) {
    int e = blockIdx.x * blockDim.x + threadIdx.x;
    if (e >= E) return;
    int d = dst[e], s = src[e];
    int pos = rowptr[d] + atomicAdd(&fill[d], 1);
    esrc[pos] = s;
    ewt[pos] = dinv[s];
}

// ---------------- gather over raw x (layer 1 input, C=6): 1 thread per node ----------------

__global__ void k_gather_x(const int* __restrict__ rowptr, const int* __restrict__ cnt,
                           const int* __restrict__ esrc, const float* __restrict__ ewt,
                           const float* __restrict__ dinv, const float* __restrict__ x,
                           float* __restrict__ out, int N) {
    int n = blockIdx.x * blockDim.x + threadIdx.x;
    if (n >= N) return;
    const float2* x2 = reinterpret_cast<const float2*>(x);
    float2* o2 = reinterpret_cast<float2*>(out);
    int beg = rowptr[n], end = beg + cnt[n];
    float di = dinv[n];
    size_t b3 = (size_t)n * 3;
    float2 p0 = x2[b3], p1 = x2[b3 + 1], p2 = x2[b3 + 2];
    float a0 = di * p0.x, a1 = di * p0.y, a2 = di * p1.x;
    float a3 = di * p1.y, a4 = di * p2.x, a5 = di * p2.y;
    for (int e = beg; e < end; ++e) {
        int s = esrc[e];
        float w = ewt[e];
        size_t s3 = (size_t)s * 3;
        float2 q0 = x2[s3], q1 = x2[s3 + 1], q2 = x2[s3 + 2];
        a0 = fmaf(w, q0.x, a0); a1 = fmaf(w, q0.y, a1);
        a2 = fmaf(w, q1.x, a2); a3 = fmaf(w, q1.y, a3);
        a4 = fmaf(w, q2.x, a4); a5 = fmaf(w, q2.y, a5);
    }
    o2[b3]     = make_float2(di * a0, di * a1);
    o2[b3 + 1] = make_float2(di * a2, di * a3);
    o2[b3 + 2] = make_float2(di * a4, di * a5);
}

// ---------------- gather with fused BN+ReLU, float4 per thread ----------------

template <int C>
__global__ void k_gather_bn(const int* __restrict__ rowptr, const int* __restrict__ cnt,
                            const int* __restrict__ esrc, const float* __restrict__ ewt,
                            const float* __restrict__ dinv, const float* __restrict__ h,
                            const float* __restrict__ sums, const float* __restrict__ sumsq,
                            const float* __restrict__ gam, const float* __restrict__ bet,
                            float* __restrict__ out, int N, float invN) {
    constexpr int TPN = C / 4;     // threads per node
    constexpr int NPB = 256 / TPN; // nodes per block
    int t = threadIdx.x;
    int c4 = t & (TPN - 1);
    int n = blockIdx.x * NPB + t / TPN;
    if (n >= N) return;
    float4 sm = reinterpret_cast<const float4*>(sums)[c4];
    float4 sq = reinterpret_cast<const float4*>(sumsq)[c4];
    float4 ga = reinterpret_cast<const float4*>(gam)[c4];
    float4 bt = reinterpret_cast<const float4*>(bet)[c4];
    float4 sc, sh;
    bnparam(sm.x, sq.x, ga.x, bt.x, invN, sc.x, sh.x);
    bnparam(sm.y, sq.y, ga.y, bt.y, invN, sc.y, sh.y);
    bnparam(sm.z, sq.z, ga.z, bt.z, invN, sc.z, sh.z);
    bnparam(sm.w, sq.w, ga.w, bt.w, invN, sc.w, sh.w);
    const float4* h4 = reinterpret_cast<const float4*>(h);
    int beg = rowptr[n], end = beg + cnt[n];
    float di = dinv[n];
    float4 acc = f4scale(di, bnrelu4(h4[(size_t)n * TPN + c4], sc, sh));  // self-loop
    int e = beg;
    for (; e + 1 < end; e += 2) {
        int s0 = esrc[e], s1 = esrc[e + 1];
        float w0 = ewt[e], w1 = ewt[e + 1];
        float4 v0 = h4[(size_t)s0 * TPN + c4];
        float4 v1 = h4[(size_t)s1 * TPN + c4];
        acc = f4fma(w0, bnrelu4(v0, sc, sh), acc);
        acc = f4fma(w1, bnrelu4(v1, sc, sh), acc);
    }
    if (e < end)
        acc = f4fma(ewt[e], bnrelu4(h4[(size_t)esrc[e] * TPN + c4], sc, sh), acc);
    reinterpret_cast<float4*>(out)[(size_t)n * TPN + c4] = f4scale(di, acc);
}

// ---------------- LDS-tiled matmul + fused BN-stats ----------------
// Each block owns a contiguous ROWS-row tile. Input tile and W staged in LDS
// via dense coalesced loads; compute reads LDS only; coalesced float4 writes.

template <int CIN, int COUT, int ROWS>
__global__ void k_mm_stats(const float* __restrict__ in, const float* __restrict__ W,
                           float* __restrict__ out, float* __restrict__ sums,
                           float* __restrict__ sumsq, int N) {
    constexpr int CG = COUT / 4;   // thread-groups of 4 output channels
    constexpr int RPB = 256 / CG;  // rows computed in parallel
    __shared__ float inT[ROWS * CIN];
    __shared__ float4 wT[CIN * CG];
    __shared__ float4 red1[256];
    __shared__ float4 red2[256];
    int t = threadIdx.x;
    // stage W (coalesced float4)
    const float4* W4 = reinterpret_cast<const float4*>(W);
    for (int i = t; i < CIN * CG; i += 256) wT[i] = W4[i];
    // stage input tile (dense coalesced)
    int base = blockIdx.x * ROWS;
    int nrows = min(ROWS, N - base);
    if constexpr (CIN % 4 == 0) {
        const float4* in4 = reinterpret_cast<const float4*>(in + (size_t)base * CIN);
        float4* inT4 = reinterpret_cast<float4*>(inT);
        int tot = nrows * (CIN / 4);
        for (int i = t; i < tot; i += 256) inT4[i] = in4[i];
    } else {  // CIN=6: float2 path
        const float2* in2 = reinterpret_cast<const float2*>(in + (size_t)base * CIN);
        float2* inT2 = reinterpret_cast<float2*>(inT);
        int tot = nrows * (CIN / 2);
        for (int i = t; i < tot; i += 256) inT2[i] = in2[i];
    }
    __syncthreads();
    int gi = t % CG, r0 = t / CG, c0 = gi * 4;
    float4 s = {0, 0, 0, 0}, s2 = {0, 0, 0, 0};
    for (int r = r0; r < nrows; r += RPB) {
        const float* row = inT + r * CIN;
        float4 acc = {0, 0, 0, 0};
#pragma unroll
        for (int k = 0; k < CIN; ++k) acc = f4fma(row[k], wT[k * CG + gi], acc);
        reinterpret_cast<float4*>(out + (size_t)(base + r) * COUT)[gi] = acc;
        s = f4add(s, acc);
        s2.x = fmaf(acc.x, acc.x, s2.x);
        s2.y = fmaf(acc.y, acc.y, s2.y);
        s2.z = fmaf(acc.z, acc.z, s2.z);
        s2.w = fmaf(acc.w, acc.w, s2.w);
    }
    red1[t] = s; red2[t] = s2;
    for (int hh = RPB / 2; hh > 0; hh >>= 1) {
        __syncthreads();
        if (r0 < hh) {
            red1[t] = f4add(red1[t], red1[t + hh * CG]);
            red2[t] = f4add(red2[t], red2[t + hh * CG]);
        }
    }
    if (r0 == 0) {
        float4 a = red1[t], b = red2[t];
        atomicAdd(&sums[c0 + 0], a.x); atomicAdd(&sums[c0 + 1], a.y);
        atomicAdd(&sums[c0 + 2], a.z); atomicAdd(&sums[c0 + 3], a.w);
        atomicAdd(&sumsq[c0 + 0], b.x); atomicAdd(&sumsq[c0 + 1], b.y);
        atomicAdd(&sumsq[c0 + 2], b.z); atomicAdd(&sumsq[c0 + 3], b.w);
    }
}

// ---------------- segmented segment_max with fused BN+ReLU (batch is sorted) ----------------

__global__ void k_segmax_bn(const float* __restrict__ h, const int* __restrict__ batch,
                            const float* __restrict__ sums, const float* __restrict__ sumsq,
                            const float* __restrict__ gam, const float* __restrict__ bet,
                            float* __restrict__ pool, int N, float invN) {
    int t = threadIdx.x;
    int c = t & 127;
    int sub = t >> 7;
    int base = blockIdx.x * 64 + sub * 32;
    if (base >= N) return;
    float sc, sh;
    bnparam(sums[c], sumsq[c], gam[c], bet[c], invN, sc, sh);
    int cur = batch[base];
    float mx = fmaxf(fmaf(sc, h[(size_t)base * 128 + c], sh), 0.f);
    int lim = min(32, N - base);
    for (int i = 1; i < lim; ++i) {
        int n = base + i;
        int b = batch[n];
        float v = fmaxf(fmaf(sc, h[(size_t)n * 128 + c], sh), 0.f);
        if (b != cur) {  // uniform across the 128 lanes of this sub-chunk
            atomicMax(reinterpret_cast<int*>(pool) + (cur << 7) + c, __float_as_int(mx));
            cur = b; mx = v;
        } else {
            mx = fmaxf(mx, v);
        }
    }
    atomicMax(reinterpret_cast<int*>(pool) + (cur << 7) + c, __float_as_int(mx));
}

// ---------------- head: BN4+ReLU on load, FC2, row-L2-normalize ----------------

__global__ void k_head(const float* __restrict__ Z, const float* __restrict__ sums,
                       const float* __restrict__ sumsq, const float* __restrict__ gam,
                       const float* __restrict__ bet, const float* __restrict__ Wf2,
                       const float* __restrict__ bf2, float* __restrict__ out) {
    int g = blockIdx.x, c = threadIdx.x;  // 64 threads = 1 wave
    __shared__ float row[128];
    const float invG = 1.0f / (float)NG;
    for (int j = c; j < 128; j += 64) {
        float sc, sh;
        bnparam(sums[j], sumsq[j], gam[j], bet[j], invG, sc, sh);
        row[j] = fmaxf(fmaf(sc, Z[(g << 7) + j], sh), 0.f);
    }
    __syncthreads();
    float acc = bf2[c];
#pragma unroll
    for (int k = 0; k < 128; ++k) acc = fmaf(row[k], Wf2[k * 64 + c], acc);
    float ss = acc * acc;
#pragma unroll
    for (int off = 32; off; off >>= 1) ss += __shfl_xor(ss, off);
    out[(g << 6) + c] = acc / fmaxf(sqrtf(ss), 1e-12f);
}

// ---------------- launch ----------------

extern "C" void kernel_launch(void* const* d_in, const int* in_sizes, int n_in,
                              void* d_out, int out_size, void* d_ws, size_t ws_size,
                              hipStream_t stream) {
    const float* x    = (const float*)d_in[0];
    const int*   src  = (const int*)d_in[1];
    const int*   dst  = (const int*)d_in[2];
    const int*   batch= (const int*)d_in[3];
    const float* W1   = (const float*)d_in[4];   // b1 cancels in BN
    const float* g1   = (const float*)d_in[6];
    const float* be1  = (const float*)d_in[7];
    const float* W2   = (const float*)d_in[8];   // b2 cancels
    const float* g2   = (const float*)d_in[10];
    const float* be2  = (const float*)d_in[11];
    const float* W3   = (const float*)d_in[12];  // b3 cancels
    const float* g3   = (const float*)d_in[14];
    const float* be3  = (const float*)d_in[15];
    const float* Wf1  = (const float*)d_in[16];  // bf1 cancels
    const float* g4   = (const float*)d_in[18];
    const float* be4  = (const float*)d_in[19];
    const float* Wf2  = (const float*)d_in[20];
    const float* bf2  = (const float*)d_in[21];
    float* out = (float*)d_out;

    const int N = in_sizes[0] / 6;
    const int E = in_sizes[1];
    const int nScanBlocks = (N + SCAN_T * SCAN_I - 1) / (SCAN_T * SCAN_I);

    // workspace carve-up
    char* ws = (char*)d_ws;
    size_t off = 0;
    auto carve = [&](size_t bytes) {
        void* p = ws + off;
        off += (bytes + 255) & ~(size_t)255;
        return p;
    };
    int*   cnt    = (int*)carve((size_t)N * 4);
    float* dinv   = (float*)carve((size_t)N * 4);
    int*   rowptr = (int*)carve((size_t)N * 4);
    int*   fill   = (int*)carve((size_t)N * 4);
    int*   bsum   = (int*)carve((size_t)4096 * 4);
    int*   esrc   = (int*)carve((size_t)E * 4);
    float* ewt    = (float*)carve((size_t)E * 4);
    float* G      = (float*)carve((size_t)N * 64 * 4);   // gather outputs (max C=64)
    float* H      = (float*)carve((size_t)N * 128 * 4);  // matmul outputs (max C=128)
    float* stats  = (float*)carve(704 * 4);
    float* pool   = (float*)carve((size_t)NG * 128 * 4);
    float* Z      = (float*)carve((size_t)NG * 128 * 4);
    float* s1 = stats;        // L1 sums/sumsq
    float* s2 = stats + 64;   // L2
    float* s3 = stats + 192;  // L3
    float* s4 = stats + 448;  // head

    const float invN = 1.0f / (float)N;

    // ---- build dst-sorted CSR (once; reused by all 3 layers) ----
    hipMemsetAsync(cnt, 0, (size_t)N * 4, stream);
    hipMemsetAsync(fill, 0, (size_t)N * 4, stream);
    hipMemsetAsync(stats, 0, 704 * 4, stream);
    hipMemsetAsync(pool, 0, (size_t)NG * 128 * 4, stream);
    k_count<<<(E + 255) / 256, 256, 0, stream>>>(dst, cnt, E);
    k_dinv<<<(N + 255) / 256, 256, 0, stream>>>(cnt, dinv, N);
    k_scan1<<<nScanBlocks, SCAN_T, 0, stream>>>(cnt, rowptr, bsum, N);
    k_scan2<<<1, SCAN_T, 0, stream>>>(bsum, nScanBlocks);
    k_scan3<<<nScanBlocks, SCAN_T, 0, stream>>>(rowptr, bsum, N);
    k_bucket<<<(E + 255) / 256, 256, 0, stream>>>(src, dst, dinv, rowptr, fill, esrc, ewt, E);

    // ---- layer 1: aggregate x (C=6), then 6->32 matmul (+stats1) ----
    k_gather_x<<<(N + 255) / 256, 256, 0, stream>>>(rowptr, cnt, esrc, ewt, dinv, x, G, N);
    k_mm_stats<6, 32, 256><<<(N + 255) / 256, 256, 0, stream>>>(G, W1, H, s1, s1 + 32, N);

    // ---- layer 2: aggregate act1 (C=32), then 32->64 matmul (+stats2) ----
    k_gather_bn<32><<<(N + 31) / 32, 256, 0, stream>>>(
        rowptr, cnt, esrc, ewt, dinv, H, s1, s1 + 32, g1, be1, G, N, invN);
    k_mm_stats<32, 64, 128><<<(N + 127) / 128, 256, 0, stream>>>(G, W2, H, s2, s2 + 64, N);

    // ---- layer 3: aggregate act2 (C=64), then 64->128 matmul (+stats3) ----
    k_gather_bn<64><<<(N + 15) / 16, 256, 0, stream>>>(
        rowptr, cnt, esrc, ewt, dinv, H, s2, s2 + 64, g2, be2, G, N, invN);
    k_mm_stats<64, 128, 128><<<(N + 127) / 128, 256, 0, stream>>>(G, W3, H, s3, s3 + 128, N);

    // ---- pooling: segmented segment_max with fused BN3+ReLU ----
    k_segmax_bn<<<(N + 63) / 64, 256, 0, stream>>>(H, batch, s3, s3 + 128, g3, be3, pool, N, invN);

    // ---- head: FC1 (+stats4), then BN4+ReLU+FC2+normalize ----
    k_mm_stats<128, 128, 64><<<(NG + 63) / 64, 256, 0, stream>>>(pool, Wf1, Z, s4, s4 + 128, NG);
    k_head<<<NG, 64, 0, stream>>>(Z, s4, s4 + 128, g4, be4, Wf2, bf2, out);
}

// Round 6
// 958.145 us; speedup vs baseline: 1.4193x; 1.2332x over previous
//
#include <hip/hip_runtime.h>
#include <hip/hip_bf16.h>

#define NG 512  // NUM_GRAPHS
#define EPS_BN 1e-5f

__device__ __forceinline__ float4 f4add(float4 a, float4 b) {
    a.x += b.x; a.y += b.y; a.z += b.z; a.w += b.w; return a;
}
__device__ __forceinline__ float4 f4fma(float s, float4 b, float4 a) {
    a.x = fmaf(s, b.x, a.x); a.y = fmaf(s, b.y, a.y);
    a.z = fmaf(s, b.z, a.z); a.w = fmaf(s, b.w, a.w); return a;
}
__device__ __forceinline__ float4 f4scale(float s, float4 a) {
    a.x *= s; a.y *= s; a.z *= s; a.w *= s; return a;
}
__device__ __forceinline__ float4 bnrelu4(float4 v, float4 sc, float4 sh) {
    float4 r;
    r.x = fmaxf(fmaf(sc.x, v.x, sh.x), 0.f);
    r.y = fmaxf(fmaf(sc.y, v.y, sh.y), 0.f);
    r.z = fmaxf(fmaf(sc.z, v.z, sh.z), 0.f);
    r.w = fmaxf(fmaf(sc.w, v.w, sh.w), 0.f);
    return r;
}
__device__ __forceinline__ void bnparam(float sm, float sq, float ga, float bt,
                                        float invN, float& sc, float& sh) {
    float m = sm * invN;
    float var = fmaf(-m, m, sq * invN);
    sc = ga * rsqrtf(var + EPS_BN);
    sh = fmaf(-m, sc, bt);
}

// ---------------- degree / normalization ----------------

__global__ void k_count(const int* __restrict__ dst, int* __restrict__ cnt, int E) {
    int i = blockIdx.x * blockDim.x + threadIdx.x;
    if (i < E) atomicAdd(&cnt[dst[i]], 1);
}

__global__ void k_dinv(const int* __restrict__ cnt, float* __restrict__ dinv, int N) {
    int i = blockIdx.x * blockDim.x + threadIdx.x;
    if (i < N) dinv[i] = rsqrtf((float)cnt[i] + 1.0f);  // +1 self-loop
}

// ---------------- exclusive prefix-sum over cnt -> rowptr ----------------

#define SCAN_T 256
#define SCAN_I 4  // 1024 elements per block

__global__ void k_scan1(const int* __restrict__ in, int* __restrict__ out,
                        int* __restrict__ bsum, int N) {
    __shared__ int lds[SCAN_T];
    int t = threadIdx.x;
    int base = blockIdx.x * (SCAN_T * SCAN_I) + t * SCAN_I;
    int v[SCAN_I];
    int sum = 0;
#pragma unroll
    for (int i = 0; i < SCAN_I; ++i) {
        int idx = base + i;
        v[i] = (idx < N) ? in[idx] : 0;
        sum += v[i];
    }
    lds[t] = sum;
    __syncthreads();
    for (int o = 1; o < SCAN_T; o <<= 1) {
        int a = (t >= o) ? lds[t - o] : 0;
        __syncthreads();
        lds[t] += a;
        __syncthreads();
    }
    int run = lds[t] - sum;
#pragma unroll
    for (int i = 0; i < SCAN_I; ++i) {
        int idx = base + i;
        if (idx < N) out[idx] = run;
        run += v[i];
    }
    if (t == SCAN_T - 1) bsum[blockIdx.x] = lds[SCAN_T - 1];
}

__global__ void k_scan2(int* __restrict__ bs, int nb) {
    __shared__ int lds[SCAN_T];
    int t = threadIdx.x;
    int runbase = 0;
    for (int start = 0; start < nb; start += SCAN_T) {
        int idx = start + t;
        int v = (idx < nb) ? bs[idx] : 0;
        lds[t] = v;
        __syncthreads();
        for (int o = 1; o < SCAN_T; o <<= 1) {
            int a = (t >= o) ? lds[t - o] : 0;
            __syncthreads();
            lds[t] += a;
            __syncthreads();
        }
        if (idx < nb) bs[idx] = runbase + lds[t] - v;
        int tot = lds[SCAN_T - 1];
        __syncthreads();
        runbase += tot;
    }
}

__global__ void k_scan3(int* __restrict__ out, const int* __restrict__ bs, int N) {
    int add = bs[blockIdx.x];
    int base = blockIdx.x * (SCAN_T * SCAN_I) + threadIdx.x * SCAN_I;
#pragma unroll
    for (int i = 0; i < SCAN_I; ++i) {
        int idx = base + i;
        if (idx < N) out[idx] += add;
    }
}

// ---------------- bucket edges by dst (CSR), pre-bake per-edge weight dinv[src] ----------------

__global__ void k_bucket(const int* __restrict__ src, const int* __restrict__ dst,
                         const float* __restrict__ dinv, const int* __restrict__ rowptr,
                         int* __restrict__ fill, int* __restrict__ esrc,
                         float* __restrict__ ewt, int E) {
    int e = blockIdx.x * blockDim.x + threadIdx.x;
    if (e >= E) return;
    int d = dst[e], s = src[e];
    int pos = rowptr[d] + atomicAdd(&fill[d], 1);
    esrc[pos] = s;
    ewt[pos] = dinv[s];
}

// ---------------- fused layer 1: gather raw x (C=6, 1 thread/node) + mm 6->COUT + stats ----------------

template <int COUT>
__global__ __launch_bounds__(256) void k_layer1(
    const int* __restrict__ rowptr, const int* __restrict__ cnt,
    const int* __restrict__ esrc, const float* __restrict__ ewt,
    const float* __restrict__ dinv, const float* __restrict__ x,
    const float* __restrict__ W, float* __restrict__ hout,
    float* __restrict__ sums, float* __restrict__ sumsq, int N) {
    constexpr int NPB = 256;
    constexpr int CG = COUT / 4;   // 8
    constexpr int RPB = 256 / CG;  // 32
    __shared__ float4 inT4[NPB * 6 / 4];
    float* inT = (float*)inT4;
    __shared__ float4 wT[6 * CG];
    __shared__ float4 red[256];
    int t = threadIdx.x;
    const float4* W4 = (const float4*)W;
    for (int i = t; i < 6 * CG; i += 256) wT[i] = W4[i];
    int base = blockIdx.x * NPB;
    int n = base + t;
    if (n < N) {
        const float2* x2 = (const float2*)x;
        int beg = rowptr[n], end = beg + cnt[n];
        float di = dinv[n];
        size_t b3 = (size_t)n * 3;
        float2 p0 = x2[b3], p1 = x2[b3 + 1], p2 = x2[b3 + 2];
        float a0 = di * p0.x, a1 = di * p0.y, a2 = di * p1.x;
        float a3 = di * p1.y, a4 = di * p2.x, a5 = di * p2.y;
        for (int e = beg; e < end; ++e) {
            int s = esrc[e];
            float w = ewt[e];
            size_t s3 = (size_t)s * 3;
            float2 q0 = x2[s3], q1 = x2[s3 + 1], q2 = x2[s3 + 2];
            a0 = fmaf(w, q0.x, a0); a1 = fmaf(w, q0.y, a1);
            a2 = fmaf(w, q1.x, a2); a3 = fmaf(w, q1.y, a3);
            a4 = fmaf(w, q2.x, a4); a5 = fmaf(w, q2.y, a5);
        }
        int o = t * 6;
        inT[o + 0] = di * a0; inT[o + 1] = di * a1; inT[o + 2] = di * a2;
        inT[o + 3] = di * a3; inT[o + 4] = di * a4; inT[o + 5] = di * a5;
    }
    __syncthreads();
    int gi = t % CG, r0 = t / CG, c0 = gi * 4;
    int nrows = min(NPB, N - base);
    float4 s = {0, 0, 0, 0}, s2 = {0, 0, 0, 0};
    for (int r = r0; r < nrows; r += RPB) {
        const float* row = inT + r * 6;
        float4 acc = {0, 0, 0, 0};
#pragma unroll
        for (int k = 0; k < 6; ++k) acc = f4fma(row[k], wT[k * CG + gi], acc);
        reinterpret_cast<float4*>(hout + (size_t)(base + r) * COUT)[gi] = acc;
        s = f4add(s, acc);
        s2.x = fmaf(acc.x, acc.x, s2.x);
        s2.y = fmaf(acc.y, acc.y, s2.y);
        s2.z = fmaf(acc.z, acc.z, s2.z);
        s2.w = fmaf(acc.w, acc.w, s2.w);
    }
    red[t] = s;
    for (int hh = RPB / 2; hh > 0; hh >>= 1) {
        __syncthreads();
        if (r0 < hh) red[t] = f4add(red[t], red[t + hh * CG]);
    }
    if (r0 == 0) {
        float4 a = red[t];
        atomicAdd(&sums[c0 + 0], a.x); atomicAdd(&sums[c0 + 1], a.y);
        atomicAdd(&sums[c0 + 2], a.z); atomicAdd(&sums[c0 + 3], a.w);
    }
    __syncthreads();
    red[t] = s2;
    for (int hh = RPB / 2; hh > 0; hh >>= 1) {
        __syncthreads();
        if (r0 < hh) red[t] = f4add(red[t], red[t + hh * CG]);
    }
    if (r0 == 0) {
        float4 b = red[t];
        atomicAdd(&sumsq[c0 + 0], b.x); atomicAdd(&sumsq[c0 + 1], b.y);
        atomicAdd(&sumsq[c0 + 2], b.z); atomicAdd(&sumsq[c0 + 3], b.w);
    }
}

// ---------------- fused layer: gather(+BN_prev+ReLU) + mm CIN->COUT + stats ----------------

template <int CIN, int COUT, int NPB>
__global__ __launch_bounds__(256) void k_layer(
    const int* __restrict__ rowptr, const int* __restrict__ cnt,
    const int* __restrict__ esrc, const float* __restrict__ ewt,
    const float* __restrict__ dinv, const float* __restrict__ hin,
    const float* __restrict__ sums_in, const float* __restrict__ sumsq_in,
    const float* __restrict__ gam, const float* __restrict__ bet,
    const float* __restrict__ W, float* __restrict__ hout,
    float* __restrict__ sums_out, float* __restrict__ sumsq_out,
    int N, float invN) {
    constexpr int TPN = CIN / 4;
    constexpr int ITER1 = NPB * TPN / 256;
    constexpr int NPI = 256 / TPN;  // nodes gathered per iteration
    constexpr int CG = COUT / 4;
    constexpr int RPB = 256 / CG;
    __shared__ float4 inT4[NPB * TPN];
    float* inT = (float*)inT4;
    __shared__ float4 wT[CIN * CG];
    __shared__ float4 red[256];
    int t = threadIdx.x;
    const float4* W4 = (const float4*)W;
    for (int i = t; i < CIN * CG; i += 256) wT[i] = W4[i];
    int base = blockIdx.x * NPB;
    // ---- phase 1: gather with BN_prev+ReLU applied to loaded values ----
    {
        int c4 = t % TPN;
        float4 sm = reinterpret_cast<const float4*>(sums_in)[c4];
        float4 sq = reinterpret_cast<const float4*>(sumsq_in)[c4];
        float4 ga = reinterpret_cast<const float4*>(gam)[c4];
        float4 bt = reinterpret_cast<const float4*>(bet)[c4];
        float4 sc, sh;
        bnparam(sm.x, sq.x, ga.x, bt.x, invN, sc.x, sh.x);
        bnparam(sm.y, sq.y, ga.y, bt.y, invN, sc.y, sh.y);
        bnparam(sm.z, sq.z, ga.z, bt.z, invN, sc.z, sh.z);
        bnparam(sm.w, sq.w, ga.w, bt.w, invN, sc.w, sh.w);
        const float4* h4 = reinterpret_cast<const float4*>(hin);
#pragma unroll
        for (int it = 0; it < ITER1; ++it) {
            int nl = it * NPI + t / TPN;
            int n = base + nl;
            if (n < N) {
                int beg = rowptr[n], end = beg + cnt[n];
                float di = dinv[n];
                float4 acc = f4scale(di, bnrelu4(h4[(size_t)n * TPN + c4], sc, sh));
                int e = beg;
                for (; e + 1 < end; e += 2) {
                    int s0 = esrc[e], s1 = esrc[e + 1];
                    float w0 = ewt[e], w1 = ewt[e + 1];
                    float4 v0 = h4[(size_t)s0 * TPN + c4];
                    float4 v1 = h4[(size_t)s1 * TPN + c4];
                    acc = f4fma(w0, bnrelu4(v0, sc, sh), acc);
                    acc = f4fma(w1, bnrelu4(v1, sc, sh), acc);
                }
                if (e < end)
                    acc = f4fma(ewt[e], bnrelu4(h4[(size_t)esrc[e] * TPN + c4], sc, sh), acc);
                inT4[nl * TPN + c4] = f4scale(di, acc);
            }
        }
    }
    __syncthreads();
    // ---- phase 2: mm from LDS + BN-stats ----
    int gi = t % CG, r0 = t / CG, c0 = gi * 4;
    int nrows = min(NPB, N - base);
    float4 s = {0, 0, 0, 0}, s2 = {0, 0, 0, 0};
    for (int r = r0; r < nrows; r += RPB) {
        const float* row = inT + r * CIN;
        float4 acc = {0, 0, 0, 0};
#pragma unroll
        for (int k = 0; k < CIN; ++k) acc = f4fma(row[k], wT[k * CG + gi], acc);
        reinterpret_cast<float4*>(hout + (size_t)(base + r) * COUT)[gi] = acc;
        s = f4add(s, acc);
        s2.x = fmaf(acc.x, acc.x, s2.x);
        s2.y = fmaf(acc.y, acc.y, s2.y);
        s2.z = fmaf(acc.z, acc.z, s2.z);
        s2.w = fmaf(acc.w, acc.w, s2.w);
    }
    red[t] = s;
    for (int hh = RPB / 2; hh > 0; hh >>= 1) {
        __syncthreads();
        if (r0 < hh) red[t] = f4add(red[t], red[t + hh * CG]);
    }
    if (r0 == 0) {
        float4 a = red[t];
        atomicAdd(&sums_out[c0 + 0], a.x); atomicAdd(&sums_out[c0 + 1], a.y);
        atomicAdd(&sums_out[c0 + 2], a.z); atomicAdd(&sums_out[c0 + 3], a.w);
    }
    __syncthreads();
    red[t] = s2;
    for (int hh = RPB / 2; hh > 0; hh >>= 1) {
        __syncthreads();
        if (r0 < hh) red[t] = f4add(red[t], red[t + hh * CG]);
    }
    if (r0 == 0) {
        float4 b = red[t];
        atomicAdd(&sumsq_out[c0 + 0], b.x); atomicAdd(&sumsq_out[c0 + 1], b.y);
        atomicAdd(&sumsq_out[c0 + 2], b.z); atomicAdd(&sumsq_out[c0 + 3], b.w);
    }
}

// ---------------- head matmul (pool @ Wf1) + stats, LDS-tiled ----------------

template <int CIN, int COUT, int ROWS>
__global__ __launch_bounds__(256) void k_mm_stats(
    const float* __restrict__ in, const float* __restrict__ W,
    float* __restrict__ out, float* __restrict__ sums,
    float* __restrict__ sumsq, int N) {
    constexpr int CG = COUT / 4;
    constexpr int RPB = 256 / CG;
    __shared__ float4 inT4[ROWS * CIN / 4];
    float* inT = (float*)inT4;
    __shared__ float4 wT[CIN * CG];
    __shared__ float4 red[256];
    int t = threadIdx.x;
    const float4* W4 = reinterpret_cast<const float4*>(W);
    for (int i = t; i < CIN * CG; i += 256) wT[i] = W4[i];
    int base = blockIdx.x * ROWS;
    int nrows = min(ROWS, N - base);
    {
        const float4* in4 = reinterpret_cast<const float4*>(in + (size_t)base * CIN);
        int tot = nrows * (CIN / 4);
        for (int i = t; i < tot; i += 256) inT4[i] = in4[i];
    }
    __syncthreads();
    int gi = t % CG, r0 = t / CG, c0 = gi * 4;
    float4 s = {0, 0, 0, 0}, s2 = {0, 0, 0, 0};
    for (int r = r0; r < nrows; r += RPB) {
        const float* row = inT + r * CIN;
        float4 acc = {0, 0, 0, 0};
#pragma unroll
        for (int k = 0; k < CIN; ++k) acc = f4fma(row[k], wT[k * CG + gi], acc);
        reinterpret_cast<float4*>(out + (size_t)(base + r) * COUT)[gi] = acc;
        s = f4add(s, acc);
        s2.x = fmaf(acc.x, acc.x, s2.x);
        s2.y = fmaf(acc.y, acc.y, s2.y);
        s2.z = fmaf(acc.z, acc.z, s2.z);
        s2.w = fmaf(acc.w, acc.w, s2.w);
    }
    red[t] = s;
    for (int hh = RPB / 2; hh > 0; hh >>= 1) {
        __syncthreads();
        if (r0 < hh) red[t] = f4add(red[t], red[t + hh * CG]);
    }
    if (r0 == 0) {
        float4 a = red[t];
        atomicAdd(&sums[c0 + 0], a.x); atomicAdd(&sums[c0 + 1], a.y);
        atomicAdd(&sums[c0 + 2], a.z); atomicAdd(&sums[c0 + 3], a.w);
    }
    __syncthreads();
    red[t] = s2;
    for (int hh = RPB / 2; hh > 0; hh >>= 1) {
        __syncthreads();
        if (r0 < hh) red[t] = f4add(red[t], red[t + hh * CG]);
    }
    if (r0 == 0) {
        float4 b = red[t];
        atomicAdd(&sumsq[c0 + 0], b.x); atomicAdd(&sumsq[c0 + 1], b.y);
        atomicAdd(&sumsq[c0 + 2], b.z); atomicAdd(&sumsq[c0 + 3], b.w);
    }
}

// ---------------- segmented segment_max with fused BN+ReLU (batch is sorted) ----------------

__global__ void k_segmax_bn(const float* __restrict__ h, const int* __restrict__ batch,
                            const float* __restrict__ sums, const float* __restrict__ sumsq,
                            const float* __restrict__ gam, const float* __restrict__ bet,
                            float* __restrict__ pool, int N, float invN) {
    int t = threadIdx.x;
    int c = t & 127;
    int sub = t >> 7;
    int base = blockIdx.x * 64 + sub * 32;
    if (base >= N) return;
    float sc, sh;
    bnparam(sums[c], sumsq[c], gam[c], bet[c], invN, sc, sh);
    int cur = batch[base];
    float mx = fmaxf(fmaf(sc, h[(size_t)base * 128 + c], sh), 0.f);
    int lim = min(32, N - base);
    for (int i = 1; i < lim; ++i) {
        int n = base + i;
        int b = batch[n];
        float v = fmaxf(fmaf(sc, h[(size_t)n * 128 + c], sh), 0.f);
        if (b != cur) {
            atomicMax(reinterpret_cast<int*>(pool) + (cur << 7) + c, __float_as_int(mx));
            cur = b; mx = v;
        } else {
            mx = fmaxf(mx, v);
        }
    }
    atomicMax(reinterpret_cast<int*>(pool) + (cur << 7) + c, __float_as_int(mx));
}

// ---------------- head: BN4+ReLU on load, FC2, row-L2-normalize ----------------

__global__ void k_head(const float* __restrict__ Z, const float* __restrict__ sums,
                       const float* __restrict__ sumsq, const float* __restrict__ gam,
                       const float* __restrict__ bet, const float* __restrict__ Wf2,
                       const float* __restrict__ bf2, float* __restrict__ out) {
    int g = blockIdx.x, c = threadIdx.x;  // 64 threads = 1 wave
    __shared__ float row[128];
    const float invG = 1.0f / (float)NG;
    for (int j = c; j < 128; j += 64) {
        float sc, sh;
        bnparam(sums[j], sumsq[j], gam[j], bet[j], invG, sc, sh);
        row[j] = fmaxf(fmaf(sc, Z[(g << 7) + j], sh), 0.f);
    }
    __syncthreads();
    float acc = bf2[c];
#pragma unroll
    for (int k = 0; k < 128; ++k) acc = fmaf(row[k], Wf2[k * 64 + c], acc);
    float ss = acc * acc;
#pragma unroll
    for (int off = 32; off; off >>= 1) ss += __shfl_xor(ss, off);
    out[(g << 6) + c] = acc / fmaxf(sqrtf(ss), 1e-12f);
}

// ---------------- launch ----------------

extern "C" void kernel_launch(void* const* d_in, const int* in_sizes, int n_in,
                              void* d_out, int out_size, void* d_ws, size_t ws_size,
                              hipStream_t stream) {
    const float* x    = (const float*)d_in[0];
    const int*   src  = (const int*)d_in[1];
    const int*   dst  = (const int*)d_in[2];
    const int*   batch= (const int*)d_in[3];
    const float* W1   = (const float*)d_in[4];   // b1 cancels in BN
    const float* g1   = (const float*)d_in[6];
    const float* be1  = (const float*)d_in[7];
    const float* W2   = (const float*)d_in[8];   // b2 cancels
    const float* g2   = (const float*)d_in[10];
    const float* be2  = (const float*)d_in[11];
    const float* W3   = (const float*)d_in[12];  // b3 cancels
    const float* g3   = (const float*)d_in[14];
    const float* be3  = (const float*)d_in[15];
    const float* Wf1  = (const float*)d_in[16];  // bf1 cancels
    const float* g4   = (const float*)d_in[18];
    const float* be4  = (const float*)d_in[19];
    const float* Wf2  = (const float*)d_in[20];
    const float* bf2  = (const float*)d_in[21];
    float* out = (float*)d_out;

    const int N = in_sizes[0] / 6;
    const int E = in_sizes[1];
    const int nScanBlocks = (N + SCAN_T * SCAN_I - 1) / (SCAN_T * SCAN_I);

    // workspace carve-up
    char* ws = (char*)d_ws;
    size_t off = 0;
    auto carve = [&](size_t bytes) {
        void* p = ws + off;
        off += (bytes + 255) & ~(size_t)255;
        return p;
    };
    int*   cnt    = (int*)carve((size_t)N * 4);
    float* dinv   = (float*)carve((size_t)N * 4);
    int*   rowptr = (int*)carve((size_t)N * 4);
    int*   fill   = (int*)carve((size_t)N * 4);
    int*   bsum   = (int*)carve((size_t)4096 * 4);
    int*   esrc   = (int*)carve((size_t)E * 4);
    float* ewt    = (float*)carve((size_t)E * 4);
    float* H1     = (float*)carve((size_t)N * 32 * 4);   // layer-1 output
    float* H2     = (float*)carve((size_t)N * 64 * 4);   // layer-2 output
    float* H3     = (float*)carve((size_t)N * 128 * 4);  // layer-3 output
    float* stats  = (float*)carve(704 * 4);
    float* pool   = (float*)carve((size_t)NG * 128 * 4);
    float* Z      = (float*)carve((size_t)NG * 128 * 4);
    float* s1 = stats;        // L1 sums/sumsq (32+32)
    float* s2 = stats + 64;   // L2 (64+64)
    float* s3 = stats + 192;  // L3 (128+128)
    float* s4 = stats + 448;  // head (128+128)

    const float invN = 1.0f / (float)N;

    // ---- build dst-sorted CSR (once; reused by all 3 layers) ----
    hipMemsetAsync(cnt, 0, (size_t)N * 4, stream);
    hipMemsetAsync(fill, 0, (size_t)N * 4, stream);
    hipMemsetAsync(stats, 0, 704 * 4, stream);
    hipMemsetAsync(pool, 0, (size_t)NG * 128 * 4, stream);
    k_count<<<(E + 255) / 256, 256, 0, stream>>>(dst, cnt, E);
    k_dinv<<<(N + 255) / 256, 256, 0, stream>>>(cnt, dinv, N);
    k_scan1<<<nScanBlocks, SCAN_T, 0, stream>>>(cnt, rowptr, bsum, N);
    k_scan2<<<1, SCAN_T, 0, stream>>>(bsum, nScanBlocks);
    k_scan3<<<nScanBlocks, SCAN_T, 0, stream>>>(rowptr, bsum, N);
    k_bucket<<<(E + 255) / 256, 256, 0, stream>>>(src, dst, dinv, rowptr, fill, esrc, ewt, E);

    // ---- layer 1 fused: gather x (C=6) + mm 6->32 + stats1 -> H1 ----
    k_layer1<32><<<(N + 255) / 256, 256, 0, stream>>>(
        rowptr, cnt, esrc, ewt, dinv, x, W1, H1, s1, s1 + 32, N);

    // ---- layer 2 fused: gather bnrelu1(H1) (C=32) + mm 32->64 + stats2 -> H2 ----
    k_layer<32, 64, 64><<<(N + 63) / 64, 256, 0, stream>>>(
        rowptr, cnt, esrc, ewt, dinv, H1, s1, s1 + 32, g1, be1, W2, H2,
        s2, s2 + 64, N, invN);

    // ---- layer 3 fused: gather bnrelu2(H2) (C=64) + mm 64->128 + stats3 -> H3 ----
    k_layer<64, 128, 64><<<(N + 63) / 64, 256, 0, stream>>>(
        rowptr, cnt, esrc, ewt, dinv, H2, s2, s2 + 64, g2, be2, W3, H3,
        s3, s3 + 128, N, invN);

    // ---- pooling: segmented segment_max with fused BN3+ReLU ----
    k_segmax_bn<<<(N + 63) / 64, 256, 0, stream>>>(H3, batch, s3, s3 + 128, g3, be3, pool, N, invN);

    // ---- head: FC1 (+stats4), then BN4+ReLU+FC2+normalize ----
    k_mm_stats<128, 128, 64><<<(NG + 63) / 64, 256, 0, stream>>>(pool, Wf1, Z, s4, s4 + 128, NG);
    k_head<<<NG, 64, 0, stream>>>(Z, s4, s4 + 128, g4, be4, Wf2, bf2, out);
}

// Round 7
// 813.242 us; speedup vs baseline: 1.6722x; 1.1782x over previous
//
#include <hip/hip_runtime.h>
#include <hip/hip_bf16.h>

#define NG 512  // NUM_GRAPHS
#define EPS_BN 1e-5f

__device__ __forceinline__ float4 f4add(float4 a, float4 b) {
    a.x += b.x; a.y += b.y; a.z += b.z; a.w += b.w; return a;
}
__device__ __forceinline__ float4 f4fma(float s, float4 b, float4 a) {
    a.x = fmaf(s, b.x, a.x); a.y = fmaf(s, b.y, a.y);
    a.z = fmaf(s, b.z, a.z); a.w = fmaf(s, b.w, a.w); return a;
}
__device__ __forceinline__ float4 f4scale(float s, float4 a) {
    a.x *= s; a.y *= s; a.z *= s; a.w *= s; return a;
}
__device__ __forceinline__ float4 bnrelu4(float4 v, float4 sc, float4 sh) {
    float4 r;
    r.x = fmaxf(fmaf(sc.x, v.x, sh.x), 0.f);
    r.y = fmaxf(fmaf(sc.y, v.y, sh.y), 0.f);
    r.z = fmaxf(fmaf(sc.z, v.z, sh.z), 0.f);
    r.w = fmaxf(fmaf(sc.w, v.w, sh.w), 0.f);
    return r;
}
__device__ __forceinline__ void bnparam(float sm, float sq, float ga, float bt,
                                        float invN, float& sc, float& sh) {
    float m = sm * invN;
    float var = fmaf(-m, m, sq * invN);
    sc = ga * rsqrtf(var + EPS_BN);
    sh = fmaf(-m, sc, bt);
}

// ---------------- degree / normalization ----------------

__global__ void k_count(const int* __restrict__ dst, int* __restrict__ cnt, int E) {
    int i = blockIdx.x * blockDim.x + threadIdx.x;
    if (i < E) atomicAdd(&cnt[dst[i]], 1);
}

__global__ void k_dinv(const int* __restrict__ cnt, float* __restrict__ dinv, int N) {
    int i = blockIdx.x * blockDim.x + threadIdx.x;
    if (i < N) dinv[i] = rsqrtf((float)cnt[i] + 1.0f);  // +1 self-loop
}

// ---------------- exclusive prefix-sum over cnt -> rowptr ----------------

#define SCAN_T 256
#define SCAN_I 4  // 1024 elements per block

__global__ void k_scan1(const int* __restrict__ in, int* __restrict__ out,
                        int* __restrict__ bsum, int N) {
    __shared__ int lds[SCAN_T];
    int t = threadIdx.x;
    int base = blockIdx.x * (SCAN_T * SCAN_I) + t * SCAN_I;
    int v[SCAN_I];
    int sum = 0;
#pragma unroll
    for (int i = 0; i < SCAN_I; ++i) {
        int idx = base + i;
        v[i] = (idx < N) ? in[idx] : 0;
        sum += v[i];
    }
    lds[t] = sum;
    __syncthreads();
    for (int o = 1; o < SCAN_T; o <<= 1) {
        int a = (t >= o) ? lds[t - o] : 0;
        __syncthreads();
        lds[t] += a;
        __syncthreads();
    }
    int run = lds[t] - sum;
#pragma unroll
    for (int i = 0; i < SCAN_I; ++i) {
        int idx = base + i;
        if (idx < N) out[idx] = run;
        run += v[i];
    }
    if (t == SCAN_T - 1) bsum[blockIdx.x] = lds[SCAN_T - 1];
}

__global__ void k_scan2(int* __restrict__ bs, int nb) {
    __shared__ int lds[SCAN_T];
    int t = threadIdx.x;
    int runbase = 0;
    for (int start = 0; start < nb; start += SCAN_T) {
        int idx = start + t;
        int v = (idx < nb) ? bs[idx] : 0;
        lds[t] = v;
        __syncthreads();
        for (int o = 1; o < SCAN_T; o <<= 1) {
            int a = (t >= o) ? lds[t - o] : 0;
            __syncthreads();
            lds[t] += a;
            __syncthreads();
        }
        if (idx < nb) bs[idx] = runbase + lds[t] - v;
        int tot = lds[SCAN_T - 1];
        __syncthreads();
        runbase += tot;
    }
}

__global__ void k_scan3(int* __restrict__ out, const int* __restrict__ bs, int N) {
    int add = bs[blockIdx.x];
    int base = blockIdx.x * (SCAN_T * SCAN_I) + threadIdx.x * SCAN_I;
#pragma unroll
    for (int i = 0; i < SCAN_I; ++i) {
        int idx = base + i;
        if (idx < N) out[idx] += add;
    }
}

// ---------------- bucket edges by dst (CSR), pre-bake per-edge weight dinv[src] ----------------

__global__ void k_bucket(const int* __restrict__ src, const int* __restrict__ dst,
                         const float* __restrict__ dinv, const int* __restrict__ rowptr,
                         int* __restrict__ fill, int* __restrict__ esrc,
                         float* __restrict__ ewt, int E) {
    int e = blockIdx.x * blockDim.x + threadIdx.x;
    if (e >= E) return;
    int d = dst[e], s = src[e];
    int pos = rowptr[d] + atomicAdd(&fill[d], 1);
    esrc[pos] = s;
    ewt[pos] = dinv[s];
}

// ---------------- fused layer 1: gather raw x (C=6, 1 thread/node) + mm 6->COUT + stats ----------------

template <int COUT>
__global__ __launch_bounds__(256) void k_layer1(
    const int* __restrict__ rowptr, const int* __restrict__ cnt,
    const int* __restrict__ esrc, const float* __restrict__ ewt,
    const float* __restrict__ dinv, const float* __restrict__ x,
    const float* __restrict__ W, float* __restrict__ hout,
    float* __restrict__ sums, float* __restrict__ sumsq, int N) {
    constexpr int NPB = 256;
    constexpr int CG = COUT / 4;   // 8
    constexpr int RPB = 256 / CG;  // 32
    __shared__ float4 inT4[NPB * 6 / 4];
    float* inT = (float*)inT4;
    __shared__ float4 wT[6 * CG];
    __shared__ float4 red[256];
    int t = threadIdx.x;
    const float4* W4 = (const float4*)W;
    for (int i = t; i < 6 * CG; i += 256) wT[i] = W4[i];
    int base = blockIdx.x * NPB;
    int n = base + t;
    if (n < N) {
        const float2* x2 = (const float2*)x;
        int beg = rowptr[n], end = beg + cnt[n];
        float di = dinv[n];
        size_t b3 = (size_t)n * 3;
        float2 p0 = x2[b3], p1 = x2[b3 + 1], p2 = x2[b3 + 2];
        float a0 = di * p0.x, a1 = di * p0.y, a2 = di * p1.x;
        float a3 = di * p1.y, a4 = di * p2.x, a5 = di * p2.y;
        for (int e = beg; e < end; ++e) {
            int s = esrc[e];
            float w = ewt[e];
            size_t s3 = (size_t)s * 3;
            float2 q0 = x2[s3], q1 = x2[s3 + 1], q2 = x2[s3 + 2];
            a0 = fmaf(w, q0.x, a0); a1 = fmaf(w, q0.y, a1);
            a2 = fmaf(w, q1.x, a2); a3 = fmaf(w, q1.y, a3);
            a4 = fmaf(w, q2.x, a4); a5 = fmaf(w, q2.y, a5);
        }
        int o = t * 6;
        inT[o + 0] = di * a0; inT[o + 1] = di * a1; inT[o + 2] = di * a2;
        inT[o + 3] = di * a3; inT[o + 4] = di * a4; inT[o + 5] = di * a5;
    }
    __syncthreads();
    int gi = t % CG, r0 = t / CG, c0 = gi * 4;
    int nrows = min(NPB, N - base);
    float4 s = {0, 0, 0, 0}, s2 = {0, 0, 0, 0};
    for (int r = r0; r < nrows; r += RPB) {
        const float* row = inT + r * 6;
        float4 acc = {0, 0, 0, 0};
#pragma unroll
        for (int k = 0; k < 6; ++k) acc = f4fma(row[k], wT[k * CG + gi], acc);
        reinterpret_cast<float4*>(hout + (size_t)(base + r) * COUT)[gi] = acc;
        s = f4add(s, acc);
        s2.x = fmaf(acc.x, acc.x, s2.x);
        s2.y = fmaf(acc.y, acc.y, s2.y);
        s2.z = fmaf(acc.z, acc.z, s2.z);
        s2.w = fmaf(acc.w, acc.w, s2.w);
    }
    red[t] = s;
    for (int hh = RPB / 2; hh > 0; hh >>= 1) {
        __syncthreads();
        if (r0 < hh) red[t] = f4add(red[t], red[t + hh * CG]);
    }
    if (r0 == 0) {
        float4 a = red[t];
        atomicAdd(&sums[c0 + 0], a.x); atomicAdd(&sums[c0 + 1], a.y);
        atomicAdd(&sums[c0 + 2], a.z); atomicAdd(&sums[c0 + 3], a.w);
    }
    __syncthreads();
    red[t] = s2;
    for (int hh = RPB / 2; hh > 0; hh >>= 1) {
        __syncthreads();
        if (r0 < hh) red[t] = f4add(red[t], red[t + hh * CG]);
    }
    if (r0 == 0) {
        float4 b = red[t];
        atomicAdd(&sumsq[c0 + 0], b.x); atomicAdd(&sumsq[c0 + 1], b.y);
        atomicAdd(&sumsq[c0 + 2], b.z); atomicAdd(&sumsq[c0 + 3], b.w);
    }
}

// ---------------- fused layer: gather(+BN_prev+ReLU) + mm CIN->COUT + stats ----------------
// No W LDS staging (global reads, L1/L2-resident). Padded LDS rows. Unroll-4 gather.

template <int CIN, int COUT, int NPB>
__global__ __launch_bounds__(256, 5) void k_layer(
    const int* __restrict__ rowptr, const int* __restrict__ cnt,
    const int* __restrict__ esrc, const float* __restrict__ ewt,
    const float* __restrict__ dinv, const float* __restrict__ hin,
    const float* __restrict__ sums_in, const float* __restrict__ sumsq_in,
    const float* __restrict__ gam, const float* __restrict__ bet,
    const float* __restrict__ W, float* __restrict__ hout,
    float* __restrict__ sums_out, float* __restrict__ sumsq_out,
    int N, float invN) {
    constexpr int TPN = CIN / 4;      // threads cooperating on one node (gather)
    constexpr int PAD = TPN + 1;      // padded row stride in float4
    constexpr int ITER1 = NPB * TPN / 256;
    constexpr int NPI = 256 / TPN;    // nodes gathered per iteration
    constexpr int CG = COUT / 4;
    constexpr int RPB = 256 / CG;
    __shared__ float4 inT4[NPB * PAD];
    __shared__ float4 red[256];
    int t = threadIdx.x;
    const float4* W4 = (const float4*)W;
    int base = blockIdx.x * NPB;
    // ---- phase 1: gather with BN_prev+ReLU applied to loaded values ----
    {
        int c4 = t % TPN;
        float4 sm = reinterpret_cast<const float4*>(sums_in)[c4];
        float4 sq = reinterpret_cast<const float4*>(sumsq_in)[c4];
        float4 ga = reinterpret_cast<const float4*>(gam)[c4];
        float4 bt = reinterpret_cast<const float4*>(bet)[c4];
        float4 sc, sh;
        bnparam(sm.x, sq.x, ga.x, bt.x, invN, sc.x, sh.x);
        bnparam(sm.y, sq.y, ga.y, bt.y, invN, sc.y, sh.y);
        bnparam(sm.z, sq.z, ga.z, bt.z, invN, sc.z, sh.z);
        bnparam(sm.w, sq.w, ga.w, bt.w, invN, sc.w, sh.w);
        const float4* h4 = reinterpret_cast<const float4*>(hin);
#pragma unroll
        for (int it = 0; it < ITER1; ++it) {
            int nl = it * NPI + t / TPN;
            int n = base + nl;
            if (n < N) {
                int beg = rowptr[n], end = beg + cnt[n];
                float di = dinv[n];
                float4 acc = f4scale(di, bnrelu4(h4[(size_t)n * TPN + c4], sc, sh));
                int e = beg;
                for (; e + 3 < end; e += 4) {
                    int s0 = esrc[e], s1 = esrc[e + 1], s2_ = esrc[e + 2], s3_ = esrc[e + 3];
                    float w0 = ewt[e], w1 = ewt[e + 1], w2 = ewt[e + 2], w3 = ewt[e + 3];
                    float4 v0 = h4[(size_t)s0 * TPN + c4];
                    float4 v1 = h4[(size_t)s1 * TPN + c4];
                    float4 v2 = h4[(size_t)s2_ * TPN + c4];
                    float4 v3 = h4[(size_t)s3_ * TPN + c4];
                    acc = f4fma(w0, bnrelu4(v0, sc, sh), acc);
                    acc = f4fma(w1, bnrelu4(v1, sc, sh), acc);
                    acc = f4fma(w2, bnrelu4(v2, sc, sh), acc);
                    acc = f4fma(w3, bnrelu4(v3, sc, sh), acc);
                }
                for (; e + 1 < end; e += 2) {
                    int s0 = esrc[e], s1 = esrc[e + 1];
                    float w0 = ewt[e], w1 = ewt[e + 1];
                    float4 v0 = h4[(size_t)s0 * TPN + c4];
                    float4 v1 = h4[(size_t)s1 * TPN + c4];
                    acc = f4fma(w0, bnrelu4(v0, sc, sh), acc);
                    acc = f4fma(w1, bnrelu4(v1, sc, sh), acc);
                }
                if (e < end)
                    acc = f4fma(ewt[e], bnrelu4(h4[(size_t)esrc[e] * TPN + c4], sc, sh), acc);
                inT4[nl * PAD + c4] = f4scale(di, acc);
            }
        }
    }
    __syncthreads();
    // ---- phase 2: mm from LDS (padded rows), W from global ----
    int gi = t % CG, r0 = t / CG, c0 = gi * 4;
    int nrows = min(NPB, N - base);
    float4 s = {0, 0, 0, 0}, s2 = {0, 0, 0, 0};
    for (int r = r0; r < nrows; r += RPB) {
        const float* row = (const float*)(inT4 + r * PAD);
        float4 acc = {0, 0, 0, 0};
#pragma unroll 8
        for (int k = 0; k < CIN; ++k) acc = f4fma(row[k], W4[k * CG + gi], acc);
        reinterpret_cast<float4*>(hout + (size_t)(base + r) * COUT)[gi] = acc;
        s = f4add(s, acc);
        s2.x = fmaf(acc.x, acc.x, s2.x);
        s2.y = fmaf(acc.y, acc.y, s2.y);
        s2.z = fmaf(acc.z, acc.z, s2.z);
        s2.w = fmaf(acc.w, acc.w, s2.w);
    }
    red[t] = s;
    for (int hh = RPB / 2; hh > 0; hh >>= 1) {
        __syncthreads();
        if (r0 < hh) red[t] = f4add(red[t], red[t + hh * CG]);
    }
    if (r0 == 0) {
        float4 a = red[t];
        atomicAdd(&sums_out[c0 + 0], a.x); atomicAdd(&sums_out[c0 + 1], a.y);
        atomicAdd(&sums_out[c0 + 2], a.z); atomicAdd(&sums_out[c0 + 3], a.w);
    }
    __syncthreads();
    red[t] = s2;
    for (int hh = RPB / 2; hh > 0; hh >>= 1) {
        __syncthreads();
        if (r0 < hh) red[t] = f4add(red[t], red[t + hh * CG]);
    }
    if (r0 == 0) {
        float4 b = red[t];
        atomicAdd(&sumsq_out[c0 + 0], b.x); atomicAdd(&sumsq_out[c0 + 1], b.y);
        atomicAdd(&sumsq_out[c0 + 2], b.z); atomicAdd(&sumsq_out[c0 + 3], b.w);
    }
}

// ---------------- head matmul (pool @ Wf1) + stats, LDS-tiled ----------------

template <int CIN, int COUT, int ROWS>
__global__ __launch_bounds__(256) void k_mm_stats(
    const float* __restrict__ in, const float* __restrict__ W,
    float* __restrict__ out, float* __restrict__ sums,
    float* __restrict__ sumsq, int N) {
    constexpr int CG = COUT / 4;
    constexpr int RPB = 256 / CG;
    __shared__ float4 inT4[ROWS * CIN / 4];
    float* inT = (float*)inT4;
    __shared__ float4 wT[CIN * CG];
    __shared__ float4 red[256];
    int t = threadIdx.x;
    const float4* W4 = reinterpret_cast<const float4*>(W);
    for (int i = t; i < CIN * CG; i += 256) wT[i] = W4[i];
    int base = blockIdx.x * ROWS;
    int nrows = min(ROWS, N - base);
    {
        const float4* in4 = reinterpret_cast<const float4*>(in + (size_t)base * CIN);
        int tot = nrows * (CIN / 4);
        for (int i = t; i < tot; i += 256) inT4[i] = in4[i];
    }
    __syncthreads();
    int gi = t % CG, r0 = t / CG, c0 = gi * 4;
    float4 s = {0, 0, 0, 0}, s2 = {0, 0, 0, 0};
    for (int r = r0; r < nrows; r += RPB) {
        const float* row = inT + r * CIN;
        float4 acc = {0, 0, 0, 0};
#pragma unroll
        for (int k = 0; k < CIN; ++k) acc = f4fma(row[k], wT[k * CG + gi], acc);
        reinterpret_cast<float4*>(out + (size_t)(base + r) * COUT)[gi] = acc;
        s = f4add(s, acc);
        s2.x = fmaf(acc.x, acc.x, s2.x);
        s2.y = fmaf(acc.y, acc.y, s2.y);
        s2.z = fmaf(acc.z, acc.z, s2.z);
        s2.w = fmaf(acc.w, acc.w, s2.w);
    }
    red[t] = s;
    for (int hh = RPB / 2; hh > 0; hh >>= 1) {
        __syncthreads();
        if (r0 < hh) red[t] = f4add(red[t], red[t + hh * CG]);
    }
    if (r0 == 0) {
        float4 a = red[t];
        atomicAdd(&sums[c0 + 0], a.x); atomicAdd(&sums[c0 + 1], a.y);
        atomicAdd(&sums[c0 + 2], a.z); atomicAdd(&sums[c0 + 3], a.w);
    }
    __syncthreads();
    red[t] = s2;
    for (int hh = RPB / 2; hh > 0; hh >>= 1) {
        __syncthreads();
        if (r0 < hh) red[t] = f4add(red[t], red[t + hh * CG]);
    }
    if (r0 == 0) {
        float4 b = red[t];
        atomicAdd(&sumsq[c0 + 0], b.x); atomicAdd(&sumsq[c0 + 1], b.y);
        atomicAdd(&sumsq[c0 + 2], b.z); atomicAdd(&sumsq[c0 + 3], b.w);
    }
}

// ---------------- segmented segment_max with fused BN+ReLU (batch is sorted) ----------------

__global__ void k_segmax_bn(const float* __restrict__ h, const int* __restrict__ batch,
                            const float* __restrict__ sums, const float* __restrict__ sumsq,
                            const float* __restrict__ gam, const float* __restrict__ bet,
                            float* __restrict__ pool, int N, float invN) {
    int t = threadIdx.x;
    int c = t & 127;
    int sub = t >> 7;
    int base = blockIdx.x * 64 + sub * 32;
    if (base >= N) return;
    float sc, sh;
    bnparam(sums[c], sumsq[c], gam[c], bet[c], invN, sc, sh);
    int cur = batch[base];
    float mx = fmaxf(fmaf(sc, h[(size_t)base * 128 + c], sh), 0.f);
    int lim = min(32, N - base);
    for (int i = 1; i < lim; ++i) {
        int n = base + i;
        int b = batch[n];
        float v = fmaxf(fmaf(sc, h[(size_t)n * 128 + c], sh), 0.f);
        if (b != cur) {
            atomicMax(reinterpret_cast<int*>(pool) + (cur << 7) + c, __float_as_int(mx));
            cur = b; mx = v;
        } else {
            mx = fmaxf(mx, v);
        }
    }
    atomicMax(reinterpret_cast<int*>(pool) + (cur << 7) + c, __float_as_int(mx));
}

// ---------------- head: BN4+ReLU on load, FC2, row-L2-normalize ----------------

__global__ void k_head(const float* __restrict__ Z, const float* __restrict__ sums,
                       const float* __restrict__ sumsq, const float* __restrict__ gam,
                       const float* __restrict__ bet, const float* __restrict__ Wf2,
                       const float* __restrict__ bf2, float* __restrict__ out) {
    int g = blockIdx.x, c = threadIdx.x;  // 64 threads = 1 wave
    __shared__ float row[128];
    const float invG = 1.0f / (float)NG;
    for (int j = c; j < 128; j += 64) {
        float sc, sh;
        bnparam(sums[j], sumsq[j], gam[j], bet[j], invG, sc, sh);
        row[j] = fmaxf(fmaf(sc, Z[(g << 7) + j], sh), 0.f);
    }
    __syncthreads();
    float acc = bf2[c];
#pragma unroll
    for (int k = 0; k < 128; ++k) acc = fmaf(row[k], Wf2[k * 64 + c], acc);
    float ss = acc * acc;
#pragma unroll
    for (int off = 32; off; off >>= 1) ss += __shfl_xor(ss, off);
    out[(g << 6) + c] = acc / fmaxf(sqrtf(ss), 1e-12f);
}

// ---------------- launch ----------------

extern "C" void kernel_launch(void* const* d_in, const int* in_sizes, int n_in,
                              void* d_out, int out_size, void* d_ws, size_t ws_size,
                              hipStream_t stream) {
    const float* x    = (const float*)d_in[0];
    const int*   src  = (const int*)d_in[1];
    const int*   dst  = (const int*)d_in[2];
    const int*   batch= (const int*)d_in[3];
    const float* W1   = (const float*)d_in[4];   // b1 cancels in BN
    const float* g1   = (const float*)d_in[6];
    const float* be1  = (const float*)d_in[7];
    const float* W2   = (const float*)d_in[8];   // b2 cancels
    const float* g2   = (const float*)d_in[10];
    const float* be2  = (const float*)d_in[11];
    const float* W3   = (const float*)d_in[12];  // b3 cancels
    const float* g3   = (const float*)d_in[14];
    const float* be3  = (const float*)d_in[15];
    const float* Wf1  = (const float*)d_in[16];  // bf1 cancels
    const float* g4   = (const float*)d_in[18];
    const float* be4  = (const float*)d_in[19];
    const float* Wf2  = (const float*)d_in[20];
    const float* bf2  = (const float*)d_in[21];
    float* out = (float*)d_out;

    const int N = in_sizes[0] / 6;
    const int E = in_sizes[1];
    const int nScanBlocks = (N + SCAN_T * SCAN_I - 1) / (SCAN_T * SCAN_I);

    // workspace carve-up
    char* ws = (char*)d_ws;
    size_t off = 0;
    auto carve = [&](size_t bytes) {
        void* p = ws + off;
        off += (bytes + 255) & ~(size_t)255;
        return p;
    };
    int*   cnt    = (int*)carve((size_t)N * 4);
    float* dinv   = (float*)carve((size_t)N * 4);
    int*   rowptr = (int*)carve((size_t)N * 4);
    int*   fill   = (int*)carve((size_t)N * 4);
    int*   bsum   = (int*)carve((size_t)4096 * 4);
    int*   esrc   = (int*)carve((size_t)E * 4);
    float* ewt    = (float*)carve((size_t)E * 4);
    float* H1     = (float*)carve((size_t)N * 32 * 4);   // layer-1 output
    float* H2     = (float*)carve((size_t)N * 64 * 4);   // layer-2 output
    float* H3     = (float*)carve((size_t)N * 128 * 4);  // layer-3 output
    float* stats  = (float*)carve(704 * 4);
    float* pool   = (float*)carve((size_t)NG * 128 * 4);
    float* Z      = (float*)carve((size_t)NG * 128 * 4);
    float* s1 = stats;        // L1 sums/sumsq (32+32)
    float* s2 = stats + 64;   // L2 (64+64)
    float* s3 = stats + 192;  // L3 (128+128)
    float* s4 = stats + 448;  // head (128+128)

    const float invN = 1.0f / (float)N;

    // ---- build dst-sorted CSR (once; reused by all 3 layers) ----
    hipMemsetAsync(cnt, 0, (size_t)N * 4, stream);
    hipMemsetAsync(fill, 0, (size_t)N * 4, stream);
    hipMemsetAsync(stats, 0, 704 * 4, stream);
    hipMemsetAsync(pool, 0, (size_t)NG * 128 * 4, stream);
    k_count<<<(E + 255) / 256, 256, 0, stream>>>(dst, cnt, E);
    k_dinv<<<(N + 255) / 256, 256, 0, stream>>>(cnt, dinv, N);
    k_scan1<<<nScanBlocks, SCAN_T, 0, stream>>>(cnt, rowptr, bsum, N);
    k_scan2<<<1, SCAN_T, 0, stream>>>(bsum, nScanBlocks);
    k_scan3<<<nScanBlocks, SCAN_T, 0, stream>>>(rowptr, bsum, N);
    k_bucket<<<(E + 255) / 256, 256, 0, stream>>>(src, dst, dinv, rowptr, fill, esrc, ewt, E);

    // ---- layer 1 fused: gather x (C=6) + mm 6->32 + stats1 -> H1 ----
    k_layer1<32><<<(N + 255) / 256, 256, 0, stream>>>(
        rowptr, cnt, esrc, ewt, dinv, x, W1, H1, s1, s1 + 32, N);

    // ---- layer 2 fused: gather bnrelu1(H1) (C=32) + mm 32->64 + stats2 -> H2 ----
    k_layer<32, 64, 64><<<(N + 63) / 64, 256, 0, stream>>>(
        rowptr, cnt, esrc, ewt, dinv, H1, s1, s1 + 32, g1, be1, W2, H2,
        s2, s2 + 64, N, invN);

    // ---- layer 3 fused: gather bnrelu2(H2) (C=64) + mm 64->128 + stats3 -> H3 ----
    k_layer<64, 128, 64><<<(N + 63) / 64, 256, 0, stream>>>(
        rowptr, cnt, esrc, ewt, dinv, H2, s2, s2 + 64, g2, be2, W3, H3,
        s3, s3 + 128, N, invN);

    // ---- pooling: segmented segment_max with fused BN3+ReLU ----
    k_segmax_bn<<<(N + 63) / 64, 256, 0, stream>>>(H3, batch, s3, s3 + 128, g3, be3, pool, N, invN);

    // ---- head: FC1 (+stats4), then BN4+ReLU+FC2+normalize ----
    k_mm_stats<128, 128, 64><<<(NG + 63) / 64, 256, 0, stream>>>(pool, Wf1, Z, s4, s4 + 128, NG);
    k_head<<<NG, 64, 0, stream>>>(Z, s4, s4 + 128, g4, be4, Wf2, bf2, out);
}